// Round 2
// baseline (194.277 us; speedup 1.0000x reference)
//
#include <hip/hip_runtime.h>

#define B_ 512
#define T_ 512
#define C_ 128
#define L_ 80
#define BLANK_ 127
#define EPS_ 1e-7f
#define LN2_ 0.6931471805599453f

// raw v_log_f32 (base-2); __log2f collides with glibc math.h reserved names.
#define LOG2F(x) __builtin_amdgcn_logf(x)

// DPP cross-lane ops (VALU pipe — keeps the DS pipe off the critical path).
template <int CTRL>
__device__ __forceinline__ int dpp_i(int x) {
  return __builtin_amdgcn_update_dpp(0, x, CTRL, 0xF, 0xF, true);
}
template <int CTRL>
__device__ __forceinline__ float dpp_f(float x) {
  return __int_as_float(
      __builtin_amdgcn_update_dpp(0, __float_as_int(x), CTRL, 0xF, 0xF, true));
}
#define DPP_WSHR1 0x138   // wave shift right 1 == shfl_up(1); lane0 -> 0
#define DPP_XOR1  0xB1    // quad_perm [1,0,3,2]
#define DPP_XOR2  0x4E    // quad_perm [2,3,0,1]
#define DPP_HMIRR 0x141   // row_half_mirror (within 8)
#define DPP_MIRR  0x140   // row_mirror (within 16)

// Producer/consumer wave specialization, single forward DP (verified math).
//
// 4 waves per workgroup (512 wg = 2 wg/CU = 8 waves/CU):
//   wave0: DP consumer — the exact forward recurrence of the absmax=0 kernel,
//          all 512 rows, lane i owns extended states 3i..3i+2.
//   waves1-3: producers — global float4 loads (3-phase register lead),
//          +EPS, LDS ring stage, fused row-sum denominators (Sacc).
// Ring: 4 banks x 8 rows x 128 floats. Phase k (k=0..31): consumer eats
// blocks 2k,2k+1 (banks {0,1} or {2,3}); the producer owning pair k+1 preps
// it into the opposite bank half and issues global loads for pair k+4.
// Pair P is owned by producer (P%3)+1; each producer holds one 8xfloat4
// register set, resident 3 phases (~1800 cy) >> 900 cy HBM latency.
// Barriers: 1 prologue + 32 loop + 1 epilogue = 34.
// Softmax denominator factors out: loss = ln2*(Sum log2(rowsum_t) - log2 P).
__global__ __launch_bounds__(256) void ctc_fused(
    const int* __restrict__ labels,     // [B,L]
    const float* __restrict__ y_pred,   // [B,T,C]
    float* __restrict__ out)            // [B,1]
{
  const int b = blockIdx.x, tid = threadIdx.x;
  const int wid = tid >> 6, lane = tid & 63;
  const float* gp = y_pred + (size_t)b * T_ * C_;

  __shared__ float ring[4 * 1024];      // 4 banks x 8 rows x 128 floats
  __shared__ float comb[4];             // producers' Sacc partials (1..3)

  const bool evenLane = ((lane & 1) == 0);

  // ---- consumer: static per-lane symbols + skip masks (original, verified)
  // even lane i: states blank / label k1=3i/2 / blank
  // odd  lane i: states label k0=(3i-1)/2 / blank / label k2=k0+1
  int ea = BLANK_, eb = BLANK_;
  float m0 = 0.f, m1 = 0.f, m2 = 0.f;   // allow-skip masks as 0.0/1.0
  float A0 = 0.f, A1 = 0.f, A2 = 0.f;   // DP state
  int E = 0;                            // per-lane scale: stored = true * 2^E
  if (wid == 0) {
    auto labAt = [&](int k) -> int {
      return (k >= 0 && k < L_) ? labels[b * L_ + k] : BLANK_;
    };
    if (evenLane) {
      const int k1 = (3 * lane) >> 1;
      ea = labAt(k1); eb = ea;
      m1 = ((k1 < L_) && (k1 == 0 || ea != labAt(k1 - 1))) ? 1.f : 0.f;
    } else {
      const int k0 = (3 * lane - 1) >> 1;
      const int k2 = k0 + 1;
      ea = labAt(k0); eb = labAt(k2);
      m0 = ((k0 < L_) && (k0 == 0 || ea != labAt(k0 - 1))) ? 1.f : 0.f;
      m2 = ((k2 < L_) && (eb != ea)) ? 1.f : 0.f;
    }
    // virtual init: one recurrence step from (A0=1@lane0) gives exact alpha(0)
    A0 = (lane == 0) ? 1.f : 0.f;
  }

  // ---- producer state ----
  const int rgrp = lane >> 3, j16 = lane & 7;   // row within block, slot
  float4 SA[8];                         // one pair = 2 blocks x 4 float4
  float Sacc = 0.f;                     // per-lane partial: sum log2(rowsum)

  auto loadpair = [&](int P) {          // pair P = rows 16P .. 16P+15
    #pragma unroll
    for (int h = 0; h < 2; ++h) {
      const float4* src =
          (const float4*)(gp + (size_t)(16 * P + 8 * h + rgrp) * C_) + 4 * j16;
      #pragma unroll
      for (int k = 0; k < 4; ++k) SA[4 * h + k] = src[k];
    }
  };
  // eps-add, stage to ring bank, fused row-sum (8-lane DPP reduce) + log2
  auto preppair = [&](int P) {
    #pragma unroll
    for (int h = 0; h < 2; ++h) {
      const int blk = 2 * P + h;
      float4* wd = (float4*)(ring + (blk & 3) * 1024 + rgrp * C_ + 16 * j16);
      float s = 0.f;
      #pragma unroll
      for (int k = 0; k < 4; ++k) {
        float4 v = SA[4 * h + k];
        v.x += EPS_; v.y += EPS_; v.z += EPS_; v.w += EPS_;
        wd[k] = v;
        s += (v.x + v.y) + (v.z + v.w);
      }
      s += dpp_f<DPP_XOR1>(s);
      s += dpp_f<DPP_XOR2>(s);
      s += dpp_f<DPP_HMIRR>(s);         // 8 lanes of the row share the sum
      Sacc += LOG2F(s);                 // 8x redundant; divided out at end
    }
  };

  // ---- consumer: one 8-row block (identical math to the verified kernel)
  auto stepBlock = [&](const float* g, const float* h, const float* p) {
    const int EL = dpp_i<DPP_WSHR1>(E); // left lane's exponent (lane0 -> 0)
    const int d = E - EL;               // block-constant reconcile shift
    #pragma unroll
    for (int j = 0; j < 8; ++j) {
      const float p1 = dpp_f<DPP_WSHR1>(A1);   // left A1 (state 3i-2)
      const float p2 = dpp_f<DPP_WSHR1>(A2);   // left A2 (state 3i-1)
      const float p1p = ldexpf(p1, d);
      const float p2p = ldexpf(p2, d);
      const float q0 = evenLane ? p[j] : g[j];
      const float q1 = evenLane ? g[j] : p[j];
      const float q2 = evenLane ? p[j] : h[j];
      const float t0 = q0 * fmaf(m0, p1p, A0 + p2p);
      const float t1 = q1 * fmaf(m1, p2p, A1 + A0);
      const float t2 = q2 * fmaf(m2, A0, A2 + A1);
      A0 = t0; A1 = t1; A2 = t2;
    }
    // per-lane rescale: keep lane max ~2^0, fold into E
    const float mx = fmaxf(fmaxf(A0, A1), A2);
    int ee = (int)((__float_as_uint(mx) >> 23) & 255u) - 127;
    const bool z = (mx == 0.f);
    ee = z ? 0 : ee;
    A0 = ldexpf(A0, -ee); A1 = ldexpf(A1, -ee); A2 = ldexpf(A2, -ee);
    E = z ? EL : (E - ee);              // virgin lanes track left neighbor's E
  };

  // ---- prologue: producers load pairs 0..2; owner preps pair 0, loads 3 ----
  if (wid != 0) {
    loadpair(wid - 1);
    if (wid == 1) { preppair(0); loadpair(3); }
  }
  __syncthreads();

  // ---- main loop: 32 phases, 2 blocks each ----
  for (int k = 0; k < 32; ++k) {
    if (wid == 0) {
      const float* rb0 = ring + ((2 * k) & 3) * 1024;
      const float* rb1 = ring + ((2 * k + 1) & 3) * 1024;
      float gA[8], hA[8], pA[8], gB[8], hB[8], pB[8];
      #pragma unroll
      for (int j = 0; j < 8; ++j) {     // gathers for both blocks up front
        gA[j] = rb0[j * C_ + ea];
        hA[j] = rb0[j * C_ + eb];
        pA[j] = rb0[j * C_ + BLANK_];   // same addr all lanes: LDS broadcast
      }
      #pragma unroll
      for (int j = 0; j < 8; ++j) {
        gB[j] = rb1[j * C_ + ea];
        hB[j] = rb1[j * C_ + eb];
        pB[j] = rb1[j * C_ + BLANK_];
      }
      stepBlock(gA, hA, pA);
      stepBlock(gB, hB, pB);
    } else {
      const int P = k + 1;              // pair consumed next phase
      if (P < 32 && (P % 3) == (wid - 1)) {
        preppair(P);                    // stage into opposite bank half
        if (P + 3 < 32) loadpair(P + 3);// 3-phase register lead
      }
    }
    __syncthreads();
  }

  // ---- epilogue: denominator partials (each row counted 8x -> *0.125) ----
  if (wid != 0) {
    float s = Sacc;
    s += dpp_f<DPP_XOR1>(s);
    s += dpp_f<DPP_XOR2>(s);
    s += dpp_f<DPP_HMIRR>(s);
    s += dpp_f<DPP_MIRR>(s);
    s += __shfl_xor(s, 16, 64);
    s += __shfl_xor(s, 32, 64);
    if (lane == 0) comb[wid] = s * 0.125f;
  }
  __syncthreads();

  // loss = ln2 * (S - (log2(A159+A160) - E));  lane 53: A0=s159, A1=s160
  if (wid == 0 && lane == 53) {
    const float Stot = comb[1] + comb[2] + comb[3];
    out[b] = LN2_ * (Stot - (LOG2F(A0 + A1) - (float)E));
  }
}

extern "C" void kernel_launch(void* const* d_in, const int* in_sizes, int n_in,
                              void* d_out, int out_size, void* d_ws, size_t ws_size,
                              hipStream_t stream) {
  const int*   labels = (const int*)d_in[0];    // y_true [B,L]
  const float* y_pred = (const float*)d_in[1];  // y_pred [B,T,C]
  float*       out    = (float*)d_out;          // [B,1]
  ctc_fused<<<dim3(B_), dim3(256), 0, stream>>>(labels, y_pred, out);
}

// Round 3
// 193.602 us; speedup vs baseline: 1.0035x; 1.0035x over previous
//
#include <hip/hip_runtime.h>

#define B_ 512
#define T_ 512
#define C_ 128
#define L_ 80
#define BLANK_ 127
#define EPS_ 1e-7f
#define LN2_ 0.6931471805599453f

// raw v_log_f32 (base-2); __log2f collides with glibc math.h reserved names.
#define LOG2F(x) __builtin_amdgcn_logf(x)

// DPP cross-lane ops (VALU pipe — keeps the DS pipe off the critical path).
template <int CTRL>
__device__ __forceinline__ int dpp_i(int x) {
  return __builtin_amdgcn_update_dpp(0, x, CTRL, 0xF, 0xF, true);
}
template <int CTRL>
__device__ __forceinline__ float dpp_f(float x) {
  return __int_as_float(
      __builtin_amdgcn_update_dpp(0, __float_as_int(x), CTRL, 0xF, 0xF, true));
}
#define DPP_WSHR1 0x138   // wave shift right 1 == shfl_up(1); lane0 -> 0
#define DPP_XOR1  0xB1    // quad_perm [1,0,3,2]
#define DPP_XOR2  0x4E    // quad_perm [2,3,0,1]
#define DPP_HMIRR 0x141   // row_half_mirror (within 8)
#define DPP_MIRR  0x140   // row_mirror (within 16)

// Counted barrier: drains ONLY lgkmcnt (LDS producer->consumer visibility),
// leaves global loads IN FLIGHT across the barrier. __syncthreads() would
// emit s_waitcnt vmcnt(0) before s_barrier, forcing the producer that just
// issued its 3-phase-lead loads to eat ~900cy HBM latency on the critical
// path of EVERY phase (the round-2 pathology: phases ~2800cy instead of
// ~1600cy). asm "memory" clobber + sched_barrier(0) pin compiler memory-op
// motion across the barrier (rule #18); the compiler's own counted vmcnt(N)
// before each SA register use orders the global loads (3-phase lead -> free).
__device__ __forceinline__ void wg_barrier() {
  __builtin_amdgcn_sched_barrier(0);
  asm volatile("s_waitcnt lgkmcnt(0)" ::: "memory");
  __builtin_amdgcn_s_barrier();
  __builtin_amdgcn_sched_barrier(0);
}

// Producer/consumer wave specialization, single forward DP (verified math).
//
// 4 waves per workgroup (512 wg = 2 wg/CU = 8 waves/CU):
//   wave0: DP consumer — the exact forward recurrence of the absmax=0 kernel,
//          all 512 rows, lane i owns extended states 3i..3i+2.
//   waves1-3: producers — global float4 loads (3-phase register lead),
//          +EPS, LDS ring stage, fused row-sum denominators (Sacc).
// Ring: 4 banks x 8 rows x 128 floats. Phase k (k=0..31): consumer eats
// blocks 2k,2k+1 (banks {0,1} or {2,3}); the producer owning pair k+1 preps
// it into the opposite bank half and issues global loads for pair k+4.
// Pair P is owned by producer (P%3)+1; each producer holds one 8xfloat4
// register set, resident 3 phases >> HBM latency — and with wg_barrier the
// loads actually STAY in flight across phases.
// Softmax denominator factors out: loss = ln2*(Sum log2(rowsum_t) - log2 P).
__global__ __launch_bounds__(256) void ctc_fused(
    const int* __restrict__ labels,     // [B,L]
    const float* __restrict__ y_pred,   // [B,T,C]
    float* __restrict__ out)            // [B,1]
{
  const int b = blockIdx.x, tid = threadIdx.x;
  const int wid = tid >> 6, lane = tid & 63;
  const float* gp = y_pred + (size_t)b * T_ * C_;

  __shared__ float ring[4 * 1024];      // 4 banks x 8 rows x 128 floats
  __shared__ float comb[4];             // producers' Sacc partials (1..3)

  const bool evenLane = ((lane & 1) == 0);

  // ---- consumer: static per-lane symbols + skip masks (original, verified)
  // even lane i: states blank / label k1=3i/2 / blank
  // odd  lane i: states label k0=(3i-1)/2 / blank / label k2=k0+1
  int ea = BLANK_, eb = BLANK_;
  float m0 = 0.f, m1 = 0.f, m2 = 0.f;   // allow-skip masks as 0.0/1.0
  float A0 = 0.f, A1 = 0.f, A2 = 0.f;   // DP state
  int E = 0;                            // per-lane scale: stored = true * 2^E
  if (wid == 0) {
    auto labAt = [&](int k) -> int {
      return (k >= 0 && k < L_) ? labels[b * L_ + k] : BLANK_;
    };
    if (evenLane) {
      const int k1 = (3 * lane) >> 1;
      ea = labAt(k1); eb = ea;
      m1 = ((k1 < L_) && (k1 == 0 || ea != labAt(k1 - 1))) ? 1.f : 0.f;
    } else {
      const int k0 = (3 * lane - 1) >> 1;
      const int k2 = k0 + 1;
      ea = labAt(k0); eb = labAt(k2);
      m0 = ((k0 < L_) && (k0 == 0 || ea != labAt(k0 - 1))) ? 1.f : 0.f;
      m2 = ((k2 < L_) && (eb != ea)) ? 1.f : 0.f;
    }
    // virtual init: one recurrence step from (A0=1@lane0) gives exact alpha(0)
    A0 = (lane == 0) ? 1.f : 0.f;
  }

  // ---- producer state ----
  const int rgrp = lane >> 3, j16 = lane & 7;   // row within block, slot
  float4 SA[8];                         // one pair = 2 blocks x 4 float4
  float Sacc = 0.f;                     // per-lane partial: sum log2(rowsum)

  auto loadpair = [&](int P) {          // pair P = rows 16P .. 16P+15
    #pragma unroll
    for (int h = 0; h < 2; ++h) {
      const float4* src =
          (const float4*)(gp + (size_t)(16 * P + 8 * h + rgrp) * C_) + 4 * j16;
      #pragma unroll
      for (int k = 0; k < 4; ++k) SA[4 * h + k] = src[k];
    }
  };
  // eps-add, stage to ring bank, fused row-sum (8-lane DPP reduce) + log2
  auto preppair = [&](int P) {
    #pragma unroll
    for (int h = 0; h < 2; ++h) {
      const int blk = 2 * P + h;
      float4* wd = (float4*)(ring + (blk & 3) * 1024 + rgrp * C_ + 16 * j16);
      float s = 0.f;
      #pragma unroll
      for (int k = 0; k < 4; ++k) {
        float4 v = SA[4 * h + k];
        v.x += EPS_; v.y += EPS_; v.z += EPS_; v.w += EPS_;
        wd[k] = v;
        s += (v.x + v.y) + (v.z + v.w);
      }
      s += dpp_f<DPP_XOR1>(s);
      s += dpp_f<DPP_XOR2>(s);
      s += dpp_f<DPP_HMIRR>(s);         // 8 lanes of the row share the sum
      Sacc += LOG2F(s);                 // 8x redundant; divided out at end
    }
  };

  // ---- consumer: one 8-row block (identical math to the verified kernel)
  auto stepBlock = [&](const float* g, const float* h, const float* p) {
    const int EL = dpp_i<DPP_WSHR1>(E); // left lane's exponent (lane0 -> 0)
    const int d = E - EL;               // block-constant reconcile shift
    #pragma unroll
    for (int j = 0; j < 8; ++j) {
      const float p1 = dpp_f<DPP_WSHR1>(A1);   // left A1 (state 3i-2)
      const float p2 = dpp_f<DPP_WSHR1>(A2);   // left A2 (state 3i-1)
      const float p1p = ldexpf(p1, d);
      const float p2p = ldexpf(p2, d);
      const float q0 = evenLane ? p[j] : g[j];
      const float q1 = evenLane ? g[j] : p[j];
      const float q2 = evenLane ? p[j] : h[j];
      const float t0 = q0 * fmaf(m0, p1p, A0 + p2p);
      const float t1 = q1 * fmaf(m1, p2p, A1 + A0);
      const float t2 = q2 * fmaf(m2, A0, A2 + A1);
      A0 = t0; A1 = t1; A2 = t2;
    }
    // per-lane rescale: keep lane max ~2^0, fold into E
    const float mx = fmaxf(fmaxf(A0, A1), A2);
    int ee = (int)((__float_as_uint(mx) >> 23) & 255u) - 127;
    const bool z = (mx == 0.f);
    ee = z ? 0 : ee;
    A0 = ldexpf(A0, -ee); A1 = ldexpf(A1, -ee); A2 = ldexpf(A2, -ee);
    E = z ? EL : (E - ee);              // virgin lanes track left neighbor's E
  };

  // ---- prologue: producers load pairs 0..2; owner preps pair 0, loads 3 ----
  if (wid != 0) {
    loadpair(wid - 1);
    if (wid == 1) { preppair(0); loadpair(3); }
  }
  wg_barrier();

  // ---- main loop: 32 phases, 2 blocks each ----
  for (int k = 0; k < 32; ++k) {
    if (wid == 0) {
      const float* rb0 = ring + ((2 * k) & 3) * 1024;
      const float* rb1 = ring + ((2 * k + 1) & 3) * 1024;
      float gA[8], hA[8], pA[8], gB[8], hB[8], pB[8];
      #pragma unroll
      for (int j = 0; j < 8; ++j) {     // gathers for both blocks up front
        gA[j] = rb0[j * C_ + ea];
        hA[j] = rb0[j * C_ + eb];
        pA[j] = rb0[j * C_ + BLANK_];   // same addr all lanes: LDS broadcast
      }
      #pragma unroll
      for (int j = 0; j < 8; ++j) {
        gB[j] = rb1[j * C_ + ea];
        hB[j] = rb1[j * C_ + eb];
        pB[j] = rb1[j * C_ + BLANK_];
      }
      stepBlock(gA, hA, pA);
      stepBlock(gB, hB, pB);
    } else {
      const int P = k + 1;              // pair consumed next phase
      if (P < 32 && (P % 3) == (wid - 1)) {
        preppair(P);                    // stage into opposite bank half
        if (P + 3 < 32) loadpair(P + 3);// 3-phase register lead, stays in
      }                                 // flight across wg_barrier
    }
    wg_barrier();
  }

  // ---- epilogue: denominator partials (each row counted 8x -> *0.125) ----
  if (wid != 0) {
    float s = Sacc;
    s += dpp_f<DPP_XOR1>(s);
    s += dpp_f<DPP_XOR2>(s);
    s += dpp_f<DPP_HMIRR>(s);
    s += dpp_f<DPP_MIRR>(s);
    s += __shfl_xor(s, 16, 64);
    s += __shfl_xor(s, 32, 64);
    if (lane == 0) comb[wid] = s * 0.125f;
  }
  wg_barrier();

  // loss = ln2 * (S - (log2(A159+A160) - E));  lane 53: A0=s159, A1=s160
  if (wid == 0 && lane == 53) {
    const float Stot = comb[1] + comb[2] + comb[3];
    out[b] = LN2_ * (Stot - (LOG2F(A0 + A1) - (float)E));
  }
}

extern "C" void kernel_launch(void* const* d_in, const int* in_sizes, int n_in,
                              void* d_out, int out_size, void* d_ws, size_t ws_size,
                              hipStream_t stream) {
  const int*   labels = (const int*)d_in[0];    // y_true [B,L]
  const float* y_pred = (const float*)d_in[1];  // y_pred [B,T,C]
  float*       out    = (float*)d_out;          // [B,1]
  ctc_fused<<<dim3(B_), dim3(256), 0, stream>>>(labels, y_pred, out);
}